// Round 1
// baseline (1004.638 us; speedup 1.0000x reference)
//
#include <hip/hip_runtime.h>
#include <stdint.h>

// Problem constants (B=4, S=4096, F=4096, O=4096, CHUNKS=4)
static constexpr int M = 16384;     // B*S rows of x
static constexpr int N = 4096;      // O
static constexpr int K = 4096;      // F
static constexpr int NCHUNK = 4;
static constexpr int CHUNK = 1024;  // K / NCHUNK

#define QMAXF 127.0f
#define EPSF 1e-8f

using i32x4 = __attribute__((ext_vector_type(4))) int;
using f32x4 = __attribute__((ext_vector_type(4))) float;

__device__ __forceinline__ void gld_lds16(const void* g, void* l) {
  __builtin_amdgcn_global_load_lds((const __attribute__((address_space(1))) void*)g,
                                   (__attribute__((address_space(3))) void*)l,
                                   16, 0, 0);
}

__device__ __forceinline__ float scale_from_bits(unsigned bits) {
  return fmaxf(__uint_as_float(bits) / QMAXF, EPSF);
}

// ---------------------------------------------------------------- absmax(w)
__global__ void wabs_kernel(const float* __restrict__ w, unsigned* __restrict__ scales) {
  const int tid = blockIdx.x * blockDim.x + threadIdx.x;
  const int stride = gridDim.x * blockDim.x;
  const float4* w4 = (const float4*)w;
  const int n4 = (N * K) / 4;
  float m = 0.f;
  for (int i = tid; i < n4; i += stride) {
    float4 v = w4[i];
    m = fmaxf(m, fmaxf(fmaxf(fabsf(v.x), fabsf(v.y)), fmaxf(fabsf(v.z), fabsf(v.w))));
  }
  #pragma unroll
  for (int off = 32; off; off >>= 1) m = fmaxf(m, __shfl_down(m, off));
  __shared__ float sm[4];
  const int lane = threadIdx.x & 63, wv = threadIdx.x >> 6;
  if (lane == 0) sm[wv] = m;
  __syncthreads();
  if (threadIdx.x == 0) {
    m = fmaxf(fmaxf(sm[0], sm[1]), fmaxf(sm[2], sm[3]));
    atomicMax(scales + 0, __float_as_uint(m));
  }
}

// ------------------------------------------------------- absmax(x) per chunk
__global__ void xabs_kernel(const float* __restrict__ x, unsigned* __restrict__ scales) {
  const int tid = blockIdx.x * blockDim.x + threadIdx.x;
  const int stride = gridDim.x * blockDim.x;
  const float4* x4 = (const float4*)x;
  const int n4 = (M * K) / 4;  // 16,777,216 float4
  float m0 = 0.f, m1 = 0.f, m2 = 0.f, m3 = 0.f;
  for (int i = tid; i < n4; i += stride) {
    float4 v = x4[i];
    float a = fmaxf(fmaxf(fabsf(v.x), fabsf(v.y)), fmaxf(fabsf(v.z), fabsf(v.w)));
    const int c = (i >> 8) & 3;  // 256 float4 per 1024-elem chunk within a 4096 row
    m0 = (c == 0) ? fmaxf(m0, a) : m0;
    m1 = (c == 1) ? fmaxf(m1, a) : m1;
    m2 = (c == 2) ? fmaxf(m2, a) : m2;
    m3 = (c == 3) ? fmaxf(m3, a) : m3;
  }
  #pragma unroll
  for (int off = 32; off; off >>= 1) {
    m0 = fmaxf(m0, __shfl_down(m0, off));
    m1 = fmaxf(m1, __shfl_down(m1, off));
    m2 = fmaxf(m2, __shfl_down(m2, off));
    m3 = fmaxf(m3, __shfl_down(m3, off));
  }
  __shared__ float sm[4][4];
  const int lane = threadIdx.x & 63, wv = threadIdx.x >> 6;
  if (lane == 0) { sm[wv][0] = m0; sm[wv][1] = m1; sm[wv][2] = m2; sm[wv][3] = m3; }
  __syncthreads();
  if (threadIdx.x < 4) {
    const int c = threadIdx.x;
    float v = fmaxf(fmaxf(sm[0][c], sm[1][c]), fmaxf(sm[2][c], sm[3][c]));
    atomicMax(scales + 1 + c, __float_as_uint(v));
  }
}

// --------------------------------------------------------------- quantize w
__global__ void quant_w_kernel(const float* __restrict__ w, const unsigned* __restrict__ scales,
                               char* __restrict__ wq) {
  const int i = blockIdx.x * blockDim.x + threadIdx.x;  // one float4 each
  const int n4 = (N * K) / 4;
  if (i >= n4) return;
  const float s = scale_from_bits(scales[0]);
  float4 v = ((const float4*)w)[i];
  int q0 = (int)fminf(fmaxf(rintf(v.x / s), -QMAXF), QMAXF);
  int q1 = (int)fminf(fmaxf(rintf(v.y / s), -QMAXF), QMAXF);
  int q2 = (int)fminf(fmaxf(rintf(v.z / s), -QMAXF), QMAXF);
  int q3 = (int)fminf(fmaxf(rintf(v.w / s), -QMAXF), QMAXF);
  unsigned packed = (unsigned)(q0 & 0xff) | ((unsigned)(q1 & 0xff) << 8) |
                    ((unsigned)(q2 & 0xff) << 16) | ((unsigned)(q3 & 0xff) << 24);
  ((unsigned*)wq)[i] = packed;
}

// --------------------------------------------------------------- quantize x
__global__ void quant_x_kernel(const float* __restrict__ x, const unsigned* __restrict__ scales,
                               char* __restrict__ xq) {
  const int i = blockIdx.x * blockDim.x + threadIdx.x;  // one float4 each
  const int n4 = (M * K) / 4;
  if (i >= n4) return;
  const int c = (i >> 8) & 3;
  const float s = scale_from_bits(scales[1 + c]);
  float4 v = ((const float4*)x)[i];
  int q0 = (int)fminf(fmaxf(rintf(v.x / s), -QMAXF), QMAXF);
  int q1 = (int)fminf(fmaxf(rintf(v.y / s), -QMAXF), QMAXF);
  int q2 = (int)fminf(fmaxf(rintf(v.z / s), -QMAXF), QMAXF);
  int q3 = (int)fminf(fmaxf(rintf(v.w / s), -QMAXF), QMAXF);
  unsigned packed = (unsigned)(q0 & 0xff) | ((unsigned)(q1 & 0xff) << 8) |
                    ((unsigned)(q2 & 0xff) << 16) | ((unsigned)(q3 & 0xff) << 24);
  ((unsigned*)xq)[i] = packed;
}

// ------------------------------------------------------------ int8 GEMM
// C[m, n] = sum_c csc[c] * (int dot over chunk c) + bias[n]
// Tiles: 128x128 per block (256 threads, 4 waves); BK = 64 bytes of K.
// Wave w -> 64x64 subtile at (wr*64, wc*64); each wave does 4x4 of 16x16x64 MFMA.
__global__ __launch_bounds__(256, 2)
void gemm_i8_kernel(const char* __restrict__ xq, const char* __restrict__ wq,
                    const float* __restrict__ bias, const unsigned* __restrict__ scales,
                    float* __restrict__ out) {
  __shared__ char As[128 * 64];
  __shared__ char Bs[128 * 64];

  const int tn = blockIdx.x;  // 0..31  (N tiles)
  const int tm = blockIdx.y;  // 0..127 (M tiles)
  const int t = threadIdx.x;
  const int lane = t & 63, wv = t >> 6;
  const int wr = wv >> 1, wc = wv & 1;
  const int l16 = lane & 15, quad = lane >> 4;

  const float wsc = scale_from_bits(scales[0]);
  float csc[NCHUNK];
  #pragma unroll
  for (int c = 0; c < NCHUNK; ++c) csc[c] = scale_from_bits(scales[1 + c]) * wsc;

  const char* aG = xq + (size_t)tm * 128 * K;
  const char* bG = wq + (size_t)tn * 128 * K;

  // staging assignments: 512 16B-lane-loads per tile, 2 per thread per matrix
  const int L0 = t, L1 = t + 256;
  char* aL0 = As + L0 * 16;  char* aL1 = As + L1 * 16;
  char* bL0 = Bs + L0 * 16;  char* bL1 = Bs + L1 * 16;
  const char* aG0 = aG + (L0 >> 2) * K + (L0 & 3) * 16;
  const char* aG1 = aG + (L1 >> 2) * K + (L1 & 3) * 16;
  const char* bG0 = bG + (L0 >> 2) * K + (L0 & 3) * 16;
  const char* bG1 = bG + (L1 >> 2) * K + (L1 & 3) * 16;

  f32x4 facc[4][4];
  #pragma unroll
  for (int mi = 0; mi < 4; ++mi)
    #pragma unroll
    for (int ni = 0; ni < 4; ++ni) facc[mi][ni] = (f32x4)(0.f);

  for (int c = 0; c < NCHUNK; ++c) {
    i32x4 iacc[4][4];
    #pragma unroll
    for (int mi = 0; mi < 4; ++mi)
      #pragma unroll
      for (int ni = 0; ni < 4; ++ni) iacc[mi][ni] = (i32x4)(0);

    for (int kk = 0; kk < CHUNK / 64; ++kk) {
      const int ko = c * CHUNK + kk * 64;
      gld_lds16(aG0 + ko, aL0);
      gld_lds16(aG1 + ko, aL1);
      gld_lds16(bG0 + ko, bL0);
      gld_lds16(bG1 + ko, bL1);
      __syncthreads();

      i32x4 af[4], bf[4];
      #pragma unroll
      for (int mi = 0; mi < 4; ++mi)
        af[mi] = *(const i32x4*)(As + ((wr * 64 + mi * 16 + l16) * 64 + quad * 16));
      #pragma unroll
      for (int ni = 0; ni < 4; ++ni)
        bf[ni] = *(const i32x4*)(Bs + ((wc * 64 + ni * 16 + l16) * 64 + quad * 16));

      #pragma unroll
      for (int mi = 0; mi < 4; ++mi)
        #pragma unroll
        for (int ni = 0; ni < 4; ++ni)
          iacc[mi][ni] = __builtin_amdgcn_mfma_i32_16x16x64_i8(af[mi], bf[ni], iacc[mi][ni], 0, 0, 0);

      __syncthreads();
    }

    const float sc = csc[c];
    #pragma unroll
    for (int mi = 0; mi < 4; ++mi)
      #pragma unroll
      for (int ni = 0; ni < 4; ++ni)
        #pragma unroll
        for (int e = 0; e < 4; ++e)
          facc[mi][ni][e] += sc * (float)iacc[mi][ni][e];
  }

  // epilogue: C/D layout (16x16 family): col = lane&15, row = quad*4 + reg
  #pragma unroll
  for (int ni = 0; ni < 4; ++ni) {
    const int col = tn * 128 + wc * 64 + ni * 16 + l16;
    const float bv = bias[col];
    #pragma unroll
    for (int mi = 0; mi < 4; ++mi) {
      const int row_base = tm * 128 + wr * 64 + mi * 16 + quad * 4;
      #pragma unroll
      for (int r = 0; r < 4; ++r)
        out[(size_t)(row_base + r) * N + col] = facc[mi][ni][r] + bv;
    }
  }
}

extern "C" void kernel_launch(void* const* d_in, const int* in_sizes, int n_in,
                              void* d_out, int out_size, void* d_ws, size_t ws_size,
                              hipStream_t stream) {
  const float* x = (const float*)d_in[0];     // [4,4096,4096] fp32
  const float* w = (const float*)d_in[1];     // [4096,4096] fp32
  const float* bias = (const float*)d_in[2];  // [4096] fp32
  float* out = (float*)d_out;                 // [4,4096,4096] fp32

  unsigned* scales = (unsigned*)d_ws;            // [0]=w absmax bits, [1..4]=x chunk absmax bits
  char* xq = (char*)d_ws + 64;                   // 64 MB int8
  char* wq = xq + (size_t)M * K;                 // 16 MB int8

  hipMemsetAsync(d_ws, 0, 64, stream);

  wabs_kernel<<<4096, 256, 0, stream>>>(w, scales);
  xabs_kernel<<<8192, 256, 0, stream>>>(x, scales);
  quant_w_kernel<<<(N * K / 4) / 256, 256, 0, stream>>>(w, scales, wq);
  quant_x_kernel<<<(M * K / 4) / 256, 256, 0, stream>>>(x, scales, xq);

  dim3 grid(N / 128, M / 128);
  gemm_i8_kernel<<<grid, 256, 0, stream>>>(xq, wq, bias, scales, out);
}

// Round 2
// 973.093 us; speedup vs baseline: 1.0324x; 1.0324x over previous
//
#include <hip/hip_runtime.h>
#include <stdint.h>

// Problem constants (B=4, S=4096, F=4096, O=4096, CHUNKS=4)
static constexpr int M = 16384;     // B*S rows of x
static constexpr int N = 4096;      // O
static constexpr int K = 4096;      // F
static constexpr int NCHUNK = 4;
static constexpr int CHUNK = 1024;  // K / NCHUNK

#define QMAXF 127.0f
#define EPSF 1e-8f

using i32x4 = __attribute__((ext_vector_type(4))) int;
using f32x4 = __attribute__((ext_vector_type(4))) float;

__device__ __forceinline__ void gld_lds16(const void* g, void* l) {
  __builtin_amdgcn_global_load_lds((const __attribute__((address_space(1))) void*)g,
                                   (__attribute__((address_space(3))) void*)l,
                                   16, 0, 0);
}

__device__ __forceinline__ float scale_from_bits(unsigned bits) {
  return fmaxf(__uint_as_float(bits) / QMAXF, EPSF);
}

// ---------------------------------------------------------------- absmax(w)
__global__ void wabs_kernel(const float* __restrict__ w, unsigned* __restrict__ scales) {
  const int tid = blockIdx.x * blockDim.x + threadIdx.x;
  const int stride = gridDim.x * blockDim.x;
  const float4* w4 = (const float4*)w;
  const int n4 = (N * K) / 4;
  float m = 0.f;
  for (int i = tid; i < n4; i += stride) {
    float4 v = w4[i];
    m = fmaxf(m, fmaxf(fmaxf(fabsf(v.x), fabsf(v.y)), fmaxf(fabsf(v.z), fabsf(v.w))));
  }
  #pragma unroll
  for (int off = 32; off; off >>= 1) m = fmaxf(m, __shfl_down(m, off));
  __shared__ float sm[4];
  const int lane = threadIdx.x & 63, wv = threadIdx.x >> 6;
  if (lane == 0) sm[wv] = m;
  __syncthreads();
  if (threadIdx.x == 0) {
    m = fmaxf(fmaxf(sm[0], sm[1]), fmaxf(sm[2], sm[3]));
    atomicMax(scales + 0, __float_as_uint(m));
  }
}

// ------------------------------------------------------- absmax(x) per chunk
__global__ void xabs_kernel(const float* __restrict__ x, unsigned* __restrict__ scales) {
  const int tid = blockIdx.x * blockDim.x + threadIdx.x;
  const int stride = gridDim.x * blockDim.x;
  const float4* x4 = (const float4*)x;
  const int n4 = (M * K) / 4;  // 16,777,216 float4
  float m0 = 0.f, m1 = 0.f, m2 = 0.f, m3 = 0.f;
  for (int i = tid; i < n4; i += stride) {
    float4 v = x4[i];
    float a = fmaxf(fmaxf(fabsf(v.x), fabsf(v.y)), fmaxf(fabsf(v.z), fabsf(v.w)));
    const int c = (i >> 8) & 3;  // 256 float4 per 1024-elem chunk within a 4096 row
    m0 = (c == 0) ? fmaxf(m0, a) : m0;
    m1 = (c == 1) ? fmaxf(m1, a) : m1;
    m2 = (c == 2) ? fmaxf(m2, a) : m2;
    m3 = (c == 3) ? fmaxf(m3, a) : m3;
  }
  #pragma unroll
  for (int off = 32; off; off >>= 1) {
    m0 = fmaxf(m0, __shfl_down(m0, off));
    m1 = fmaxf(m1, __shfl_down(m1, off));
    m2 = fmaxf(m2, __shfl_down(m2, off));
    m3 = fmaxf(m3, __shfl_down(m3, off));
  }
  __shared__ float sm[4][4];
  const int lane = threadIdx.x & 63, wv = threadIdx.x >> 6;
  if (lane == 0) { sm[wv][0] = m0; sm[wv][1] = m1; sm[wv][2] = m2; sm[wv][3] = m3; }
  __syncthreads();
  if (threadIdx.x < 4) {
    const int c = threadIdx.x;
    float v = fmaxf(fmaxf(sm[0][c], sm[1][c]), fmaxf(sm[2][c], sm[3][c]));
    atomicMax(scales + 1 + c, __float_as_uint(v));
  }
}

__device__ __forceinline__ unsigned quant_pack4(float4 v, float inv) {
  int q0 = (int)fminf(fmaxf(rintf(v.x * inv), -QMAXF), QMAXF);
  int q1 = (int)fminf(fmaxf(rintf(v.y * inv), -QMAXF), QMAXF);
  int q2 = (int)fminf(fmaxf(rintf(v.z * inv), -QMAXF), QMAXF);
  int q3 = (int)fminf(fmaxf(rintf(v.w * inv), -QMAXF), QMAXF);
  return (unsigned)(q0 & 0xff) | ((unsigned)(q1 & 0xff) << 8) |
         ((unsigned)(q2 & 0xff) << 16) | ((unsigned)(q3 & 0xff) << 24);
}

// --------------------------------------------------------------- quantize w
__global__ void quant_w_kernel(const float* __restrict__ w, const unsigned* __restrict__ scales,
                               char* __restrict__ wq) {
  const int tid = blockIdx.x * blockDim.x + threadIdx.x;
  const int stride = gridDim.x * blockDim.x;
  const int n4 = (N * K) / 4;
  const float inv = 1.0f / scale_from_bits(scales[0]);
  for (int i = tid; i < n4; i += stride) {
    float4 v = ((const float4*)w)[i];
    ((unsigned*)wq)[i] = quant_pack4(v, inv);
  }
}

// --------------------------------------------------------------- quantize x
__global__ void quant_x_kernel(const float* __restrict__ x, const unsigned* __restrict__ scales,
                               char* __restrict__ xq) {
  const int tid = blockIdx.x * blockDim.x + threadIdx.x;
  const int stride = gridDim.x * blockDim.x;
  const int n4 = (M * K) / 4;
  float inv[4];
  #pragma unroll
  for (int c = 0; c < 4; ++c) inv[c] = 1.0f / scale_from_bits(scales[1 + c]);
  for (int i = tid; i < n4; i += stride) {
    const int c = (i >> 8) & 3;
    float4 v = ((const float4*)x)[i];
    ((unsigned*)xq)[i] = quant_pack4(v, inv[c]);
  }
}

// ------------------------------------------------------------ int8 GEMM
// C[m, n] = sum_c csc[c] * (int dot over chunk c) + bias[n]
// Tiles: 128x128 per block (256 threads, 4 waves); BK = 64 bytes of K.
// Wave w -> 64x64 subtile at (wr*64, wc*64); each wave does 4x4 of 16x16x64 MFMA.
// LDS layout XOR-swizzled: global k-block kq of row r stored at LDS column
// kq ^ ((r>>1)&3). Staging bakes the swizzle into which global 16B each lane
// fetches (global_load_lds forces lane -> lds_base + lane*16). Bank check:
// within a quad, even rows -> {0..63}B half, odd rows -> {64..127}B half of the
// 128B bank period, and the swizzle spreads the 4 column slots evenly ->
// exactly 2 lanes/bank (free, m136). Unswizzled was 8-way (2.94x).
__global__ __launch_bounds__(256, 2)
void gemm_i8_kernel(const char* __restrict__ xq, const char* __restrict__ wq,
                    const float* __restrict__ bias, const unsigned* __restrict__ scales,
                    float* __restrict__ out) {
  __shared__ char As[128 * 64];
  __shared__ char Bs[128 * 64];

  const int tn = blockIdx.x;  // 0..31  (N tiles)
  const int tm = blockIdx.y;  // 0..127 (M tiles)
  const int t = threadIdx.x;
  const int lane = t & 63, wv = t >> 6;
  const int wr = wv >> 1, wc = wv & 1;
  const int l16 = lane & 15, quad = lane >> 4;

  const float wsc = scale_from_bits(scales[0]);
  float csc[NCHUNK];
  #pragma unroll
  for (int c = 0; c < NCHUNK; ++c) csc[c] = scale_from_bits(scales[1 + c]) * wsc;

  const char* aG = xq + (size_t)tm * 128 * K;
  const char* bG = wq + (size_t)tn * 128 * K;

  // staging: 512 16B-blocks per matrix; load-index L -> row L>>2, LDS col L&3,
  // global k-block (L&3) ^ ((L>>3)&3)   [(L>>3)&3 == ((row)>>1)&3]
  const int L0 = t, L1 = t + 256;
  char* aL0 = As + L0 * 16;  char* aL1 = As + L1 * 16;
  char* bL0 = Bs + L0 * 16;  char* bL1 = Bs + L1 * 16;
  const int kx0 = (L0 & 3) ^ ((L0 >> 3) & 3);
  const int kx1 = (L1 & 3) ^ ((L1 >> 3) & 3);
  const char* aG0 = aG + (L0 >> 2) * K + kx0 * 16;
  const char* aG1 = aG + (L1 >> 2) * K + kx1 * 16;
  const char* bG0 = bG + (L0 >> 2) * K + kx0 * 16;
  const char* bG1 = bG + (L1 >> 2) * K + kx1 * 16;

  // read-side swizzled column per lane (row base is a multiple of 16)
  const int rcol = (quad ^ ((l16 >> 1) & 3)) * 16;

  f32x4 facc[4][4];
  #pragma unroll
  for (int mi = 0; mi < 4; ++mi)
    #pragma unroll
    for (int ni = 0; ni < 4; ++ni) facc[mi][ni] = (f32x4)(0.f);

  for (int c = 0; c < NCHUNK; ++c) {
    i32x4 iacc[4][4];
    #pragma unroll
    for (int mi = 0; mi < 4; ++mi)
      #pragma unroll
      for (int ni = 0; ni < 4; ++ni) iacc[mi][ni] = (i32x4)(0);

    for (int kk = 0; kk < CHUNK / 64; ++kk) {
      const int ko = c * CHUNK + kk * 64;
      gld_lds16(aG0 + ko, aL0);
      gld_lds16(aG1 + ko, aL1);
      gld_lds16(bG0 + ko, bL0);
      gld_lds16(bG1 + ko, bL1);
      __syncthreads();

      i32x4 af[4], bf[4];
      #pragma unroll
      for (int mi = 0; mi < 4; ++mi)
        af[mi] = *(const i32x4*)(As + ((wr * 64 + mi * 16 + l16) * 64 + rcol));
      #pragma unroll
      for (int ni = 0; ni < 4; ++ni)
        bf[ni] = *(const i32x4*)(Bs + ((wc * 64 + ni * 16 + l16) * 64 + rcol));

      #pragma unroll
      for (int mi = 0; mi < 4; ++mi)
        #pragma unroll
        for (int ni = 0; ni < 4; ++ni)
          iacc[mi][ni] = __builtin_amdgcn_mfma_i32_16x16x64_i8(af[mi], bf[ni], iacc[mi][ni], 0, 0, 0);

      __syncthreads();
    }

    const float sc = csc[c];
    #pragma unroll
    for (int mi = 0; mi < 4; ++mi)
      #pragma unroll
      for (int ni = 0; ni < 4; ++ni)
        #pragma unroll
        for (int e = 0; e < 4; ++e)
          facc[mi][ni][e] += sc * (float)iacc[mi][ni][e];
  }

  // epilogue: C/D layout (16x16 family): col = lane&15, row = quad*4 + reg
  #pragma unroll
  for (int ni = 0; ni < 4; ++ni) {
    const int col = tn * 128 + wc * 64 + ni * 16 + l16;
    const float bv = bias[col];
    #pragma unroll
    for (int mi = 0; mi < 4; ++mi) {
      const int row_base = tm * 128 + wr * 64 + mi * 16 + quad * 4;
      #pragma unroll
      for (int r = 0; r < 4; ++r)
        out[(size_t)(row_base + r) * N + col] = facc[mi][ni][r] + bv;
    }
  }
}

extern "C" void kernel_launch(void* const* d_in, const int* in_sizes, int n_in,
                              void* d_out, int out_size, void* d_ws, size_t ws_size,
                              hipStream_t stream) {
  const float* x = (const float*)d_in[0];     // [4,4096,4096] fp32
  const float* w = (const float*)d_in[1];     // [4096,4096] fp32
  const float* bias = (const float*)d_in[2];  // [4096] fp32
  float* out = (float*)d_out;                 // [4,4096,4096] fp32

  unsigned* scales = (unsigned*)d_ws;            // [0]=w absmax bits, [1..4]=x chunk absmax bits
  char* xq = (char*)d_ws + 64;                   // 64 MB int8
  char* wq = xq + (size_t)M * K;                 // 16 MB int8

  hipMemsetAsync(d_ws, 0, 64, stream);

  wabs_kernel<<<4096, 256, 0, stream>>>(w, scales);
  xabs_kernel<<<8192, 256, 0, stream>>>(x, scales);
  quant_w_kernel<<<4096, 256, 0, stream>>>(w, scales, wq);
  quant_x_kernel<<<16384, 256, 0, stream>>>(x, scales, xq);

  dim3 grid(N / 128, M / 128);
  gemm_i8_kernel<<<grid, 256, 0, stream>>>(xq, wq, bias, scales, out);
}